// Round 4
// baseline (2089.935 us; speedup 1.0000x reference)
//
#include <hip/hip_runtime.h>

#define N_DST 100000
#define DIN 128
#define HDIM 64
#define RREL 3
#define NE 1000000

#define NBKT_REL 196              // ceil(100000/512) buckets per relation
#define NBKT (RREL * NBKT_REL)    // 588 total buckets
#define NSEG (RREL * N_DST)       // 300000 segments

// ---------------- GEMM: h = A @ W + b  (4 matrices: dst + 3 relations) ----------------
__global__ __launch_bounds__(256) void k_gemm(
    const float* __restrict__ dst_feat, const float* __restrict__ neigh,
    const float* __restrict__ Wt, const float* __restrict__ bt,
    float* __restrict__ h_dst, float* __restrict__ h_src) {
  const int RB = (N_DST + 63) / 64;  // 1563 row-blocks per matrix
  int mat = blockIdx.x / RB;
  int row0 = (blockIdx.x % RB) * 64;
  const float* A = (mat == 0) ? dst_feat : (neigh + (size_t)(mat - 1) * N_DST * DIN);
  float* Hout = (mat == 0) ? h_dst : (h_src + (size_t)(mat - 1) * N_DST * HDIM);
  const float* W = Wt + (size_t)mat * DIN * HDIM;
  const float* b = bt + mat * HDIM;

  __shared__ float Wl[DIN * HDIM];  // 32 KB
  __shared__ float Al[64 * 36];     // 64 rows x 32-k chunk, stride 36 (bank-safe)

  int tid = threadIdx.x;
  for (int i = tid * 4; i < DIN * HDIM; i += 1024)
    *(float4*)(Wl + i) = *(const float4*)(W + i);

  int tc = tid & 15;  // cols 4*tc .. 4*tc+3
  int tr = tid >> 4;  // rows 4*tr .. 4*tr+3
  float acc[4][4] = {};

  for (int k0 = 0; k0 < DIN; k0 += 32) {
    __syncthreads();
    for (int s = tid; s < 512; s += 256) {
      int r = s >> 3;
      int kq = (s & 7) << 2;
      int gr = row0 + r;
      if (gr >= N_DST) gr = N_DST - 1;  // clamp (tail block)
      *(float4*)(Al + r * 36 + kq) = *(const float4*)(A + (size_t)gr * DIN + k0 + kq);
    }
    __syncthreads();
#pragma unroll
    for (int kk = 0; kk < 32; kk += 4) {
      float4 av[4], wv[4];
#pragma unroll
      for (int i = 0; i < 4; i++) av[i] = *(float4*)(Al + (4 * tr + i) * 36 + kk);
#pragma unroll
      for (int j = 0; j < 4; j++) wv[j] = *(float4*)(Wl + (k0 + kk + j) * HDIM + 4 * tc);
#pragma unroll
      for (int i = 0; i < 4; i++) {
        const float* ap = (const float*)&av[i];
#pragma unroll
        for (int j = 0; j < 4; j++) {
          const float* wp = (const float*)&wv[j];
          float a = ap[j];
#pragma unroll
          for (int c = 0; c < 4; c++) acc[i][c] += a * wp[c];
        }
      }
    }
  }
#pragma unroll
  for (int i = 0; i < 4; i++) {
    int gr = row0 + 4 * tr + i;
    if (gr < N_DST) {
      float4 o;
      float* op = (float*)&o;
#pragma unroll
      for (int c = 0; c < 4; c++) op[c] = acc[i][c] + b[4 * tc + c];
      *(float4*)(Hout + (size_t)gr * HDIM + 4 * tc) = o;
    }
  }
}

// ---------------- per-node attention logits ----------------
__global__ __launch_bounds__(256) void k_logits(
    const float* __restrict__ h_dst, const float* __restrict__ h_src,
    const float* __restrict__ attn_l, const float* __restrict__ attn_r,
    float* __restrict__ el, float* __restrict__ er) {
  int gw = (blockIdx.x * 256 + threadIdx.x) >> 6;
  int lane = threadIdx.x & 63;
  if (gw >= 4 * N_DST) return;
  if (gw < N_DST) {
    int n = gw;
    float v = h_dst[(size_t)n * HDIM + lane];
#pragma unroll
    for (int r = 0; r < RREL; r++) {
      float p = v * attn_r[r * HDIM + lane];
#pragma unroll
      for (int o = 32; o > 0; o >>= 1) p += __shfl_xor(p, o);
      if (lane == 0) er[r * N_DST + n] = p;
    }
  } else {
    int t = gw - N_DST;
    int r = t / N_DST;
    int n = t - r * N_DST;
    float v = h_src[((size_t)r * N_DST + n) * HDIM + lane];
    float p = v * attn_l[r * HDIM + lane];
#pragma unroll
    for (int o = 32; o > 0; o >>= 1) p += __shfl_xor(p, o);
    if (lane == 0) el[r * N_DST + n] = p;
  }
}

// ---------------- CSR build, two-level bucket sort ----------------
// Buckets: (relation, dst>>9) -> 588 buckets of 512 dst nodes each. Bucket order
// matches segment order (r-major, then dst), so bucket bases align with the CSR.

// 1) coarse histogram, LDS-aggregated (avoids 3M random global atomics)
__global__ __launch_bounds__(256) void k_bcount(const int* __restrict__ dst_idx,
                                                int* __restrict__ bcounts) {
  __shared__ int h[NBKT];
  int tid = threadIdx.x;
  for (int i = tid; i < NBKT; i += 256) h[i] = 0;
  __syncthreads();
  for (int idx = blockIdx.x * 256 + tid; idx < RREL * NE; idx += gridDim.x * 256) {
    int r = idx / NE;
    int d = dst_idx[idx];
    atomicAdd(&h[r * NBKT_REL + (d >> 9)], 1);
  }
  __syncthreads();
  for (int i = tid; i < NBKT; i += 256)
    if (h[i]) atomicAdd(&bcounts[i], h[i]);
}

// 2) scan 588 bucket counts -> bucket_base[589]; init bucket_cur; offsets[NSEG]=3M
__global__ __launch_bounds__(256) void k_bscan(const int* __restrict__ bcounts,
                                               int* __restrict__ bucket_base,
                                               int* __restrict__ bucket_cur,
                                               int* __restrict__ offsets) {
  __shared__ int sm[256];
  int tid = threadIdx.x;
  int base = tid * 3;
  int c[3];
#pragma unroll
  for (int k = 0; k < 3; k++) c[k] = (base + k < NBKT) ? bcounts[base + k] : 0;
  int tsum = c[0] + c[1] + c[2];
  sm[tid] = tsum;
  __syncthreads();
  for (int off = 1; off < 256; off <<= 1) {
    int v = (tid >= off) ? sm[tid - off] : 0;
    __syncthreads();
    sm[tid] += v;
    __syncthreads();
  }
  int run = sm[tid] - tsum;
#pragma unroll
  for (int k = 0; k < 3; k++) {
    if (base + k < NBKT) {
      bucket_base[base + k] = run;
      bucket_cur[base + k] = run;
    }
    run += c[k];
  }
  if (tid == 255) bucket_base[NBKT] = sm[255];  // = RREL*NE
  if (tid == 0) offsets[NSEG] = RREL * NE;
}

// 3) bin edges: packed word (localdst<<17 | src); writes are sequential per bucket
//    cursor, so the active write window is ~588 lines -> full line utilization.
__global__ __launch_bounds__(256) void k_binning(const int* __restrict__ src_idx,
                                                 const int* __restrict__ dst_idx,
                                                 int* __restrict__ bucket_cur,
                                                 unsigned* __restrict__ tmp) {
  int idx = blockIdx.x * 256 + threadIdx.x;
  if (idx >= RREL * NE) return;
  int r = idx / NE;
  int d = dst_idx[idx];
  int s = src_idx[idx];
  int bucket = r * NBKT_REL + (d >> 9);
  int pos = atomicAdd(&bucket_cur[bucket], 1);
  tmp[pos] = ((unsigned)(d & 511) << 17) | (unsigned)s;  // src < 2^17
}

// 4) per-bucket: LDS histogram of 512 local segments + block scan -> per-segment
//    offsets + final scatter. Random writes confined to ~20 KB -> L2-combined.
__global__ __launch_bounds__(256) void k_bucket_csr(
    const int* __restrict__ bucket_base, const unsigned* __restrict__ tmp,
    int* __restrict__ src_sorted, int* __restrict__ offsets) {
  __shared__ int cnt[512];
  __shared__ int base_l[512];
  __shared__ int sm[256];
  int b = blockIdx.x;
  int r = b / NBKT_REL;
  int brel = b - r * NBKT_REL;
  int gbase = bucket_base[b];
  int gend = bucket_base[b + 1];
  int tid = threadIdx.x;
  cnt[tid] = 0;
  cnt[tid + 256] = 0;
  __syncthreads();
  for (int e = gbase + tid; e < gend; e += 256)
    atomicAdd(&cnt[tmp[e] >> 17], 1);
  __syncthreads();
  int c0 = cnt[2 * tid], c1 = cnt[2 * tid + 1];
  int tsum = c0 + c1;
  sm[tid] = tsum;
  __syncthreads();
  for (int off = 1; off < 256; off <<= 1) {
    int v = (tid >= off) ? sm[tid - off] : 0;
    __syncthreads();
    sm[tid] += v;
    __syncthreads();
  }
  int run = sm[tid] - tsum;
  base_l[2 * tid] = run;
  base_l[2 * tid + 1] = run + c0;
  __syncthreads();
  // write per-segment CSR offsets; reset cnt for reuse as scatter cursor
  for (int s = tid; s < 512; s += 256) {
    int dst = (brel << 9) + s;
    if (dst < N_DST) offsets[r * N_DST + dst] = gbase + base_l[s];
    cnt[s] = 0;
  }
  __syncthreads();
  for (int e = gbase + tid; e < gend; e += 256) {
    unsigned w = tmp[e];
    int s = w >> 17;
    int pos = gbase + base_l[s] + atomicAdd(&cnt[s], 1);
    src_sorted[pos] = (int)(w & 0x1FFFFu);
  }
}

// ---------------- GAT aggregation: one wave per (relation, dst-node) ----------------
__global__ __launch_bounds__(256) void k_aggregate(
    const int* __restrict__ offsets, const int* __restrict__ src_sorted,
    const float* __restrict__ el, const float* __restrict__ er,
    const float* __restrict__ h_src, float* __restrict__ zbuf) {
  int gw = (blockIdx.x * 256 + threadIdx.x) >> 6;
  int lane = threadIdx.x & 63;
  if (gw >= RREL * N_DST) return;
  int r = gw / N_DST;
  int start = offsets[gw], end = offsets[gw + 1];
  float erv = er[gw];
  const float* hs = h_src + (size_t)r * N_DST * HDIM;
  const float* elr = el + (size_t)r * N_DST;
  float acc = 0.f, ssum = 0.f;
  for (int base = start; base < end; base += 64) {
    int cnt = end - base;
    if (cnt > 64) cnt = 64;
    float a = 0.f;
    int sidx = 0;
    if (lane < cnt) {
      sidx = src_sorted[base + lane];
      float x = elr[sidx] + erv;
      x = (x > 0.f) ? x : 0.01f * x;  // leaky_relu
      a = __expf(x);
    }
    ssum += a;
    for (int e = 0; e < cnt; e++) {
      float ae = __shfl(a, e);
      int se = __shfl(sidx, e);
      acc += ae * hs[(size_t)se * HDIM + lane];
    }
  }
#pragma unroll
  for (int o = 32; o > 0; o >>= 1) ssum += __shfl_xor(ssum, o);
  float zv = 0.f;
  if (end > start) {
    float v = acc / ssum;
    zv = (v > 0.f) ? v : (__expf(v) - 1.f);  // elu
  }
  zbuf[(size_t)gw * HDIM + lane] = zv;
}

// ---------------- semantic attention reduce ----------------
// jj loop NOT fully unrolled (full unroll spilled: 256 VGPR + 1.5 GB scratch traffic).
__global__ __launch_bounds__(256) void k_semantic(
    const float* __restrict__ zbuf, const float* __restrict__ W1,
    const float* __restrict__ b1, const float* __restrict__ w2,
    float* __restrict__ w_acc) {
  __shared__ float W1l[64 * 128];  // 32 KB
  __shared__ float zsh[64 * 68];   // 17.4 KB, +4 pad
  __shared__ float wsum[RREL];
  int tid = threadIdx.x;
  if (tid < RREL) wsum[tid] = 0.f;
  for (int i = tid * 4; i < 64 * 128; i += 1024)
    *(float4*)(W1l + i) = *(const float4*)(W1 + i);
  long row0 = (long)blockIdx.x * 64;
  for (int t4 = tid; t4 < 1024; t4 += 256) {
    int rl = t4 >> 4;
    int j4 = (t4 & 15) << 2;
    long row = row0 + rl;
    float4 v = make_float4(0.f, 0.f, 0.f, 0.f);
    if (row < (long)NSEG) v = *(const float4*)(zbuf + row * HDIM + j4);
    *(float4*)(zsh + rl * 68 + j4) = v;
  }
  __syncthreads();
  int tc = tid & 31;
  int tr = tid >> 5;
  float acc[8][4] = {};
#pragma unroll 1
  for (int jj = 0; jj < 64; jj += 4) {
    float4 wv[4];
#pragma unroll
    for (int j = 0; j < 4; j++) wv[j] = *(float4*)(W1l + (jj + j) * 128 + 4 * tc);
#pragma unroll
    for (int ih = 0; ih < 2; ih++) {
      float4 zv[4];
#pragma unroll
      for (int i = 0; i < 4; i++) zv[i] = *(float4*)(zsh + (8 * tr + 4 * ih + i) * 68 + jj);
#pragma unroll
      for (int i = 0; i < 4; i++) {
        const float* zp = (const float*)&zv[i];
#pragma unroll
        for (int j = 0; j < 4; j++) {
          const float* wp = (const float*)&wv[j];
          float zz = zp[j];
#pragma unroll
          for (int c = 0; c < 4; c++) acc[4 * ih + i][c] += zz * wp[c];
        }
      }
    }
  }
  float b1v[4], w2v[4];
#pragma unroll
  for (int c = 0; c < 4; c++) {
    b1v[c] = b1[4 * tc + c];
    w2v[c] = w2[4 * tc + c];
  }
#pragma unroll
  for (int i = 0; i < 8; i++) {
    long row = row0 + 8 * tr + i;
    float p = 0.f;
#pragma unroll
    for (int c = 0; c < 4; c++) {
      float x = acc[i][c] + b1v[c];
      float ex = __expf(2.f * x);
      p += (1.f - 2.f / (ex + 1.f)) * w2v[c];  // tanh
    }
#pragma unroll
    for (int o = 16; o > 0; o >>= 1) p += __shfl_xor(p, o);
    if (tc == 0 && row < (long)NSEG) {
      int r = (int)(row / N_DST);
      atomicAdd(&wsum[r], p);
    }
  }
  __syncthreads();
  if (tid < RREL) atomicAdd(&w_acc[tid], wsum[tid]);
}

// ---------------- softmax over relations + weighted combine ----------------
__global__ __launch_bounds__(256) void k_final(const float* __restrict__ zbuf,
                                               const float* __restrict__ w_acc,
                                               float* __restrict__ out) {
  int idx = blockIdx.x * 256 + threadIdx.x;
  if (idx >= N_DST * HDIM / 4) return;
  const float invN = 1.0f / N_DST;
  float w0 = w_acc[0] * invN, w1 = w_acc[1] * invN, w2v = w_acc[2] * invN;
  float m = fmaxf(w0, fmaxf(w1, w2v));
  float e0 = __expf(w0 - m), e1 = __expf(w1 - m), e2 = __expf(w2v - m);
  float inv = 1.f / (e0 + e1 + e2);
  e0 *= inv; e1 *= inv; e2 *= inv;
  size_t o = (size_t)idx * 4;
  const size_t stride = (size_t)N_DST * HDIM;
  float4 z0 = *(const float4*)(zbuf + o);
  float4 z1 = *(const float4*)(zbuf + stride + o);
  float4 z2 = *(const float4*)(zbuf + 2 * stride + o);
  float4 r;
  r.x = e0 * z0.x + e1 * z1.x + e2 * z2.x;
  r.y = e0 * z0.y + e1 * z1.y + e2 * z2.y;
  r.z = e0 * z0.z + e1 * z1.z + e2 * z2.z;
  r.w = e0 * z0.w + e1 * z1.w + e2 * z2.w;
  *(float4*)(out + o) = r;
}

extern "C" void kernel_launch(void* const* d_in, const int* in_sizes, int n_in,
                              void* d_out, int out_size, void* d_ws, size_t ws_size,
                              hipStream_t stream) {
  const float* dst_feat = (const float*)d_in[0];
  const float* neigh = (const float*)d_in[1];
  const float* Wt = (const float*)d_in[2];
  const float* bt = (const float*)d_in[3];
  const float* attn_l = (const float*)d_in[4];
  const float* attn_r = (const float*)d_in[5];
  const float* W1 = (const float*)d_in[6];
  const float* b1 = (const float*)d_in[7];
  const float* w2 = (const float*)d_in[8];
  const int* src_idx = (const int*)d_in[9];
  const int* dst_idx = (const int*)d_in[10];
  float* out = (float*)d_out;

  char* p = (char*)d_ws;
  auto alloc = [&](size_t bytes) {
    char* q = p;
    p += (bytes + 255) & ~(size_t)255;
    return (void*)q;
  };
  float* h_dst = (float*)alloc((size_t)N_DST * HDIM * 4);
  float* h_src = (float*)alloc((size_t)RREL * N_DST * HDIM * 4);
  float* el = (float*)alloc((size_t)RREL * N_DST * 4);
  float* er = (float*)alloc((size_t)RREL * N_DST * 4);
  float* zbuf = (float*)alloc((size_t)RREL * N_DST * HDIM * 4);
  float* w_acc = (float*)alloc(64);
  int* offsets = (int*)alloc(((size_t)NSEG + 1) * 4);
  int* bcounts = (int*)alloc((size_t)NBKT * 4);
  int* bucket_base = (int*)alloc((size_t)(NBKT + 1) * 4);
  int* bucket_cur = (int*)alloc((size_t)NBKT * 4);
  unsigned* tmp = (unsigned*)alloc((size_t)RREL * NE * 4);
  int* src_sorted = (int*)alloc((size_t)RREL * NE * 4);

  hipMemsetAsync(bcounts, 0, (size_t)NBKT * 4, stream);
  hipMemsetAsync(w_acc, 0, 64, stream);

  k_gemm<<<4 * ((N_DST + 63) / 64), 256, 0, stream>>>(dst_feat, neigh, Wt, bt, h_dst, h_src);
  k_logits<<<(4 * N_DST * 64) / 256, 256, 0, stream>>>(h_dst, h_src, attn_l, attn_r, el, er);
  k_bcount<<<1024, 256, 0, stream>>>(dst_idx, bcounts);
  k_bscan<<<1, 256, 0, stream>>>(bcounts, bucket_base, bucket_cur, offsets);
  k_binning<<<(RREL * NE + 255) / 256, 256, 0, stream>>>(src_idx, dst_idx, bucket_cur, tmp);
  k_bucket_csr<<<NBKT, 256, 0, stream>>>(bucket_base, tmp, src_sorted, offsets);
  k_aggregate<<<(RREL * N_DST * 64) / 256, 256, 0, stream>>>(offsets, src_sorted, el, er, h_src, zbuf);
  k_semantic<<<(NSEG + 63) / 64, 256, 0, stream>>>(zbuf, W1, b1, w2, w_acc);
  k_final<<<(N_DST * HDIM / 4 + 255) / 256, 256, 0, stream>>>(zbuf, w_acc, out);
}

// Round 5
// 807.025 us; speedup vs baseline: 2.5897x; 2.5897x over previous
//
#include <hip/hip_runtime.h>

#define N_DST 100000
#define DIN 128
#define HDIM 64
#define RREL 3
#define NE 1000000

#define NBKT_REL 196              // ceil(100000/512) buckets per relation
#define NBKT (RREL * NBKT_REL)    // 588 total buckets
#define NSEG (RREL * N_DST)       // 300000 segments
#define EDGE_CHUNK 16384
#define NBLK_BIN ((RREL * NE + EDGE_CHUNK - 1) / EDGE_CHUNK)  // 184

// ---------------- GEMM: h = A @ W + b  (4 matrices: dst + 3 relations) ----------------
__global__ __launch_bounds__(256) void k_gemm(
    const float* __restrict__ dst_feat, const float* __restrict__ neigh,
    const float* __restrict__ Wt, const float* __restrict__ bt,
    float* __restrict__ h_dst, float* __restrict__ h_src) {
  const int RB = (N_DST + 63) / 64;  // 1563 row-blocks per matrix
  int mat = blockIdx.x / RB;
  int row0 = (blockIdx.x % RB) * 64;
  const float* A = (mat == 0) ? dst_feat : (neigh + (size_t)(mat - 1) * N_DST * DIN);
  float* Hout = (mat == 0) ? h_dst : (h_src + (size_t)(mat - 1) * N_DST * HDIM);
  const float* W = Wt + (size_t)mat * DIN * HDIM;
  const float* b = bt + mat * HDIM;

  __shared__ float Wl[DIN * HDIM];  // 32 KB
  __shared__ float Al[64 * 36];     // 64 rows x 32-k chunk, stride 36 (bank-safe)

  int tid = threadIdx.x;
  for (int i = tid * 4; i < DIN * HDIM; i += 1024)
    *(float4*)(Wl + i) = *(const float4*)(W + i);

  int tc = tid & 15;  // cols 4*tc .. 4*tc+3
  int tr = tid >> 4;  // rows 4*tr .. 4*tr+3
  float acc[4][4] = {};

  for (int k0 = 0; k0 < DIN; k0 += 32) {
    __syncthreads();
    for (int s = tid; s < 512; s += 256) {
      int r = s >> 3;
      int kq = (s & 7) << 2;
      int gr = row0 + r;
      if (gr >= N_DST) gr = N_DST - 1;  // clamp (tail block)
      *(float4*)(Al + r * 36 + kq) = *(const float4*)(A + (size_t)gr * DIN + k0 + kq);
    }
    __syncthreads();
#pragma unroll
    for (int kk = 0; kk < 32; kk += 4) {
      float4 av[4], wv[4];
#pragma unroll
      for (int i = 0; i < 4; i++) av[i] = *(float4*)(Al + (4 * tr + i) * 36 + kk);
#pragma unroll
      for (int j = 0; j < 4; j++) wv[j] = *(float4*)(Wl + (k0 + kk + j) * HDIM + 4 * tc);
#pragma unroll
      for (int i = 0; i < 4; i++) {
        const float* ap = (const float*)&av[i];
#pragma unroll
        for (int j = 0; j < 4; j++) {
          const float* wp = (const float*)&wv[j];
          float a = ap[j];
#pragma unroll
          for (int c = 0; c < 4; c++) acc[i][c] += a * wp[c];
        }
      }
    }
  }
#pragma unroll
  for (int i = 0; i < 4; i++) {
    int gr = row0 + 4 * tr + i;
    if (gr < N_DST) {
      float4 o;
      float* op = (float*)&o;
#pragma unroll
      for (int c = 0; c < 4; c++) op[c] = acc[i][c] + b[4 * tc + c];
      *(float4*)(Hout + (size_t)gr * HDIM + 4 * tc) = o;
    }
  }
}

// ---------------- per-node attention logits ----------------
__global__ __launch_bounds__(256) void k_logits(
    const float* __restrict__ h_dst, const float* __restrict__ h_src,
    const float* __restrict__ attn_l, const float* __restrict__ attn_r,
    float* __restrict__ el, float* __restrict__ er) {
  int gw = (blockIdx.x * 256 + threadIdx.x) >> 6;
  int lane = threadIdx.x & 63;
  if (gw >= 4 * N_DST) return;
  if (gw < N_DST) {
    int n = gw;
    float v = h_dst[(size_t)n * HDIM + lane];
#pragma unroll
    for (int r = 0; r < RREL; r++) {
      float p = v * attn_r[r * HDIM + lane];
#pragma unroll
      for (int o = 32; o > 0; o >>= 1) p += __shfl_xor(p, o);
      if (lane == 0) er[r * N_DST + n] = p;
    }
  } else {
    int t = gw - N_DST;
    int r = t / N_DST;
    int n = t - r * N_DST;
    float v = h_src[((size_t)r * N_DST + n) * HDIM + lane];
    float p = v * attn_l[r * HDIM + lane];
#pragma unroll
    for (int o = 32; o > 0; o >>= 1) p += __shfl_xor(p, o);
    if (lane == 0) el[r * N_DST + n] = p;
  }
}

// ---------------- CSR build: counting-sort partition, zero global atomics ----------------
// Buckets: (relation, dst>>9) -> 588 buckets of 512 dst nodes; bucket order == segment order.

// 1) per-chunk histogram -> hist[bucket][block] (bucket-major)
__global__ __launch_bounds__(256) void k_hist(const int* __restrict__ dst_idx,
                                              int* __restrict__ hist) {
  __shared__ int h[NBKT];
  int tid = threadIdx.x;
  int blk = blockIdx.x;
  for (int i = tid; i < NBKT; i += 256) h[i] = 0;
  __syncthreads();
  int e0 = blk * EDGE_CHUNK;
  int e1 = min(e0 + EDGE_CHUNK, RREL * NE);
  for (int idx = e0 + tid; idx < e1; idx += 256) {
    int r = idx / NE;
    int d = dst_idx[idx];
    atomicAdd(&h[r * NBKT_REL + (d >> 9)], 1);
  }
  __syncthreads();
  for (int i = tid; i < NBKT; i += 256)
    hist[(size_t)i * NBLK_BIN + blk] = h[i];
}

// 2) per-bucket exclusive scan across blocks; bucket totals out
__global__ __launch_bounds__(256) void k_colscan(int* __restrict__ hist,
                                                 int* __restrict__ bcounts) {
  __shared__ int sm[256];
  int b = blockIdx.x;
  int tid = threadIdx.x;
  int v = (tid < NBLK_BIN) ? hist[(size_t)b * NBLK_BIN + tid] : 0;
  sm[tid] = v;
  __syncthreads();
  for (int off = 1; off < 256; off <<= 1) {
    int t = (tid >= off) ? sm[tid - off] : 0;
    __syncthreads();
    sm[tid] += t;
    __syncthreads();
  }
  if (tid < NBLK_BIN) hist[(size_t)b * NBLK_BIN + tid] = sm[tid] - v;  // exclusive
  if (tid == 255) bcounts[b] = sm[255];
}

// 3) scan 588 bucket totals -> bucket_base[589]; offsets[NSEG]=3M
__global__ __launch_bounds__(256) void k_bscan(const int* __restrict__ bcounts,
                                               int* __restrict__ bucket_base,
                                               int* __restrict__ offsets) {
  __shared__ int sm[256];
  int tid = threadIdx.x;
  int base = tid * 3;
  int c[3];
#pragma unroll
  for (int k = 0; k < 3; k++) c[k] = (base + k < NBKT) ? bcounts[base + k] : 0;
  int tsum = c[0] + c[1] + c[2];
  sm[tid] = tsum;
  __syncthreads();
  for (int off = 1; off < 256; off <<= 1) {
    int v = (tid >= off) ? sm[tid - off] : 0;
    __syncthreads();
    sm[tid] += v;
    __syncthreads();
  }
  int run = sm[tid] - tsum;
#pragma unroll
  for (int k = 0; k < 3; k++) {
    if (base + k < NBKT) bucket_base[base + k] = run;
    run += c[k];
  }
  if (tid == 255) bucket_base[NBKT] = sm[255];  // = RREL*NE
  if (tid == 0) offsets[NSEG] = RREL * NE;
}

// 4) place edges: per-block LDS cursors seeded from scanned bases; LDS atomics only.
//    Packed word (localdst<<17 | src); src < 2^17, localdst < 2^9.
__global__ __launch_bounds__(256) void k_place(const int* __restrict__ src_idx,
                                               const int* __restrict__ dst_idx,
                                               const int* __restrict__ hist,
                                               const int* __restrict__ bucket_base,
                                               unsigned* __restrict__ tmp) {
  __shared__ int cur[NBKT];
  int tid = threadIdx.x;
  int blk = blockIdx.x;
  for (int i = tid; i < NBKT; i += 256)
    cur[i] = bucket_base[i] + hist[(size_t)i * NBLK_BIN + blk];
  __syncthreads();
  int e0 = blk * EDGE_CHUNK;
  int e1 = min(e0 + EDGE_CHUNK, RREL * NE);
  for (int idx = e0 + tid; idx < e1; idx += 256) {
    int r = idx / NE;
    int d = dst_idx[idx];
    int s = src_idx[idx];
    int bucket = r * NBKT_REL + (d >> 9);
    int pos = atomicAdd(&cur[bucket], 1);
    tmp[pos] = ((unsigned)(d & 511) << 17) | (unsigned)s;
  }
}

// 5) per-bucket: LDS histogram of 512 local segments + block scan -> per-segment
//    offsets + final scatter (random writes confined to ~20 KB -> L2-combined).
__global__ __launch_bounds__(256) void k_bucket_csr(
    const int* __restrict__ bucket_base, const unsigned* __restrict__ tmp,
    int* __restrict__ src_sorted, int* __restrict__ offsets) {
  __shared__ int cnt[512];
  __shared__ int base_l[512];
  __shared__ int sm[256];
  int b = blockIdx.x;
  int r = b / NBKT_REL;
  int brel = b - r * NBKT_REL;
  int gbase = bucket_base[b];
  int gend = bucket_base[b + 1];
  int tid = threadIdx.x;
  cnt[tid] = 0;
  cnt[tid + 256] = 0;
  __syncthreads();
  for (int e = gbase + tid; e < gend; e += 256)
    atomicAdd(&cnt[tmp[e] >> 17], 1);
  __syncthreads();
  int c0 = cnt[2 * tid], c1 = cnt[2 * tid + 1];
  int tsum = c0 + c1;
  sm[tid] = tsum;
  __syncthreads();
  for (int off = 1; off < 256; off <<= 1) {
    int v = (tid >= off) ? sm[tid - off] : 0;
    __syncthreads();
    sm[tid] += v;
    __syncthreads();
  }
  int run = sm[tid] - tsum;
  base_l[2 * tid] = run;
  base_l[2 * tid + 1] = run + c0;
  __syncthreads();
  for (int s = tid; s < 512; s += 256) {
    int dst = (brel << 9) + s;
    if (dst < N_DST) offsets[r * N_DST + dst] = gbase + base_l[s];
    cnt[s] = 0;
  }
  __syncthreads();
  for (int e = gbase + tid; e < gend; e += 256) {
    unsigned w = tmp[e];
    int s = w >> 17;
    int pos = gbase + base_l[s] + atomicAdd(&cnt[s], 1);
    src_sorted[pos] = (int)(w & 0x1FFFFu);
  }
}

// ---------------- GAT aggregation: one wave per (relation, dst-node) ----------------
__global__ __launch_bounds__(256) void k_aggregate(
    const int* __restrict__ offsets, const int* __restrict__ src_sorted,
    const float* __restrict__ el, const float* __restrict__ er,
    const float* __restrict__ h_src, float* __restrict__ zbuf) {
  int gw = (blockIdx.x * 256 + threadIdx.x) >> 6;
  int lane = threadIdx.x & 63;
  if (gw >= RREL * N_DST) return;
  int r = gw / N_DST;
  int start = offsets[gw], end = offsets[gw + 1];
  float erv = er[gw];
  const float* hs = h_src + (size_t)r * N_DST * HDIM;
  const float* elr = el + (size_t)r * N_DST;
  float acc = 0.f, ssum = 0.f;
  for (int base = start; base < end; base += 64) {
    int cnt = end - base;
    if (cnt > 64) cnt = 64;
    float a = 0.f;
    int sidx = 0;
    if (lane < cnt) {
      sidx = src_sorted[base + lane];
      float x = elr[sidx] + erv;
      x = (x > 0.f) ? x : 0.01f * x;  // leaky_relu
      a = __expf(x);
    }
    ssum += a;
    for (int e = 0; e < cnt; e++) {
      float ae = __shfl(a, e);
      int se = __shfl(sidx, e);
      acc += ae * hs[(size_t)se * HDIM + lane];
    }
  }
#pragma unroll
  for (int o = 32; o > 0; o >>= 1) ssum += __shfl_xor(ssum, o);
  float zv = 0.f;
  if (end > start) {
    float v = acc / ssum;
    zv = (v > 0.f) ? v : (__expf(v) - 1.f);  // elu
  }
  zbuf[(size_t)gw * HDIM + lane] = zv;
}

// ---------------- semantic attention reduce ----------------
// jj loop NOT fully unrolled (full unroll spilled: 256 VGPR + 1.5 GB scratch traffic).
__global__ __launch_bounds__(256) void k_semantic(
    const float* __restrict__ zbuf, const float* __restrict__ W1,
    const float* __restrict__ b1, const float* __restrict__ w2,
    float* __restrict__ w_acc) {
  __shared__ float W1l[64 * 128];  // 32 KB
  __shared__ float zsh[64 * 68];   // 17.4 KB, +4 pad
  __shared__ float wsum[RREL];
  int tid = threadIdx.x;
  if (tid < RREL) wsum[tid] = 0.f;
  for (int i = tid * 4; i < 64 * 128; i += 1024)
    *(float4*)(W1l + i) = *(const float4*)(W1 + i);
  long row0 = (long)blockIdx.x * 64;
  for (int t4 = tid; t4 < 1024; t4 += 256) {
    int rl = t4 >> 4;
    int j4 = (t4 & 15) << 2;
    long row = row0 + rl;
    float4 v = make_float4(0.f, 0.f, 0.f, 0.f);
    if (row < (long)NSEG) v = *(const float4*)(zbuf + row * HDIM + j4);
    *(float4*)(zsh + rl * 68 + j4) = v;
  }
  __syncthreads();
  int tc = tid & 31;
  int tr = tid >> 5;
  float acc[8][4] = {};
#pragma unroll 1
  for (int jj = 0; jj < 64; jj += 4) {
    float4 wv[4];
#pragma unroll
    for (int j = 0; j < 4; j++) wv[j] = *(float4*)(W1l + (jj + j) * 128 + 4 * tc);
#pragma unroll
    for (int ih = 0; ih < 2; ih++) {
      float4 zv[4];
#pragma unroll
      for (int i = 0; i < 4; i++) zv[i] = *(float4*)(zsh + (8 * tr + 4 * ih + i) * 68 + jj);
#pragma unroll
      for (int i = 0; i < 4; i++) {
        const float* zp = (const float*)&zv[i];
#pragma unroll
        for (int j = 0; j < 4; j++) {
          const float* wp = (const float*)&wv[j];
          float zz = zp[j];
#pragma unroll
          for (int c = 0; c < 4; c++) acc[4 * ih + i][c] += zz * wp[c];
        }
      }
    }
  }
  float b1v[4], w2v[4];
#pragma unroll
  for (int c = 0; c < 4; c++) {
    b1v[c] = b1[4 * tc + c];
    w2v[c] = w2[4 * tc + c];
  }
#pragma unroll
  for (int i = 0; i < 8; i++) {
    long row = row0 + 8 * tr + i;
    float p = 0.f;
#pragma unroll
    for (int c = 0; c < 4; c++) {
      float x = acc[i][c] + b1v[c];
      float ex = __expf(2.f * x);
      p += (1.f - 2.f / (ex + 1.f)) * w2v[c];  // tanh
    }
#pragma unroll
    for (int o = 16; o > 0; o >>= 1) p += __shfl_xor(p, o);
    if (tc == 0 && row < (long)NSEG) {
      int r = (int)(row / N_DST);
      atomicAdd(&wsum[r], p);
    }
  }
  __syncthreads();
  if (tid < RREL) atomicAdd(&w_acc[tid], wsum[tid]);
}

// ---------------- softmax over relations + weighted combine ----------------
__global__ __launch_bounds__(256) void k_final(const float* __restrict__ zbuf,
                                               const float* __restrict__ w_acc,
                                               float* __restrict__ out) {
  int idx = blockIdx.x * 256 + threadIdx.x;
  if (idx >= N_DST * HDIM / 4) return;
  const float invN = 1.0f / N_DST;
  float w0 = w_acc[0] * invN, w1 = w_acc[1] * invN, w2v = w_acc[2] * invN;
  float m = fmaxf(w0, fmaxf(w1, w2v));
  float e0 = __expf(w0 - m), e1 = __expf(w1 - m), e2 = __expf(w2v - m);
  float inv = 1.f / (e0 + e1 + e2);
  e0 *= inv; e1 *= inv; e2 *= inv;
  size_t o = (size_t)idx * 4;
  const size_t stride = (size_t)N_DST * HDIM;
  float4 z0 = *(const float4*)(zbuf + o);
  float4 z1 = *(const float4*)(zbuf + stride + o);
  float4 z2 = *(const float4*)(zbuf + 2 * stride + o);
  float4 r;
  r.x = e0 * z0.x + e1 * z1.x + e2 * z2.x;
  r.y = e0 * z0.y + e1 * z1.y + e2 * z2.y;
  r.z = e0 * z0.z + e1 * z1.z + e2 * z2.z;
  r.w = e0 * z0.w + e1 * z1.w + e2 * z2.w;
  *(float4*)(out + o) = r;
}

extern "C" void kernel_launch(void* const* d_in, const int* in_sizes, int n_in,
                              void* d_out, int out_size, void* d_ws, size_t ws_size,
                              hipStream_t stream) {
  const float* dst_feat = (const float*)d_in[0];
  const float* neigh = (const float*)d_in[1];
  const float* Wt = (const float*)d_in[2];
  const float* bt = (const float*)d_in[3];
  const float* attn_l = (const float*)d_in[4];
  const float* attn_r = (const float*)d_in[5];
  const float* W1 = (const float*)d_in[6];
  const float* b1 = (const float*)d_in[7];
  const float* w2 = (const float*)d_in[8];
  const int* src_idx = (const int*)d_in[9];
  const int* dst_idx = (const int*)d_in[10];
  float* out = (float*)d_out;

  char* p = (char*)d_ws;
  auto alloc = [&](size_t bytes) {
    char* q = p;
    p += (bytes + 255) & ~(size_t)255;
    return (void*)q;
  };
  float* h_dst = (float*)alloc((size_t)N_DST * HDIM * 4);
  float* h_src = (float*)alloc((size_t)RREL * N_DST * HDIM * 4);
  float* el = (float*)alloc((size_t)RREL * N_DST * 4);
  float* er = (float*)alloc((size_t)RREL * N_DST * 4);
  float* zbuf = (float*)alloc((size_t)RREL * N_DST * HDIM * 4);
  float* w_acc = (float*)alloc(64);
  int* offsets = (int*)alloc(((size_t)NSEG + 1) * 4);
  int* hist = (int*)alloc((size_t)NBKT * NBLK_BIN * 4);
  int* bcounts = (int*)alloc((size_t)NBKT * 4);
  int* bucket_base = (int*)alloc((size_t)(NBKT + 1) * 4);
  unsigned* tmp = (unsigned*)alloc((size_t)RREL * NE * 4);
  int* src_sorted = (int*)alloc((size_t)RREL * NE * 4);

  hipMemsetAsync(w_acc, 0, 64, stream);

  k_gemm<<<4 * ((N_DST + 63) / 64), 256, 0, stream>>>(dst_feat, neigh, Wt, bt, h_dst, h_src);
  k_logits<<<(4 * N_DST * 64) / 256, 256, 0, stream>>>(h_dst, h_src, attn_l, attn_r, el, er);
  k_hist<<<NBLK_BIN, 256, 0, stream>>>(dst_idx, hist);
  k_colscan<<<NBKT, 256, 0, stream>>>(hist, bcounts);
  k_bscan<<<1, 256, 0, stream>>>(bcounts, bucket_base, offsets);
  k_place<<<NBLK_BIN, 256, 0, stream>>>(src_idx, dst_idx, hist, bucket_base, tmp);
  k_bucket_csr<<<NBKT, 256, 0, stream>>>(bucket_base, tmp, src_sorted, offsets);
  k_aggregate<<<(RREL * N_DST * 64) / 256, 256, 0, stream>>>(offsets, src_sorted, el, er, h_src, zbuf);
  k_semantic<<<(NSEG + 63) / 64, 256, 0, stream>>>(zbuf, W1, b1, w2, w_acc);
  k_final<<<(N_DST * HDIM / 4 + 255) / 256, 256, 0, stream>>>(zbuf, w_acc, out);
}